// Round 5
// baseline (292.303 us; speedup 1.0000x reference)
//
#include <hip/hip_runtime.h>

#define EMB   256
#define NCLS  100
#define NB    64
#define NS    128
#define NL    64

// ---------------------------------------------------------------------------
// Kernel 1: sents[sid][e] = (1/NL) * sum_l emb[tok[sid,l]][e]
// One WAVE per sentence. Lane covers the 256-float row as float4 (64 lanes x
// 16B = 1KB coalesced per row). Tokens broadcast via v_readlane; loads
// batched 8-deep for MLP. AT THE ~6 TB/s L2-MISS/FABRIC WALL (88 us floor:
// identical duration from HBM or L3 — do not touch).
// ---------------------------------------------------------------------------
__global__ __launch_bounds__(256) void k_gather_mean(
    const int* __restrict__ tok, const float* __restrict__ emb,
    float* __restrict__ sents)
{
    const int w    = threadIdx.x >> 6;
    const int lane = threadIdx.x & 63;
    const int sid  = blockIdx.x * 4 + w;          // grid.x = NB*NS/4 = 2048

    const int mytok = tok[(size_t)sid * NL + lane];   // lane l holds token l

    float4 acc = make_float4(0.f, 0.f, 0.f, 0.f);
    for (int i = 0; i < NL; i += 8) {
        float4 v[8];
        #pragma unroll
        for (int j = 0; j < 8; ++j) {
            const int tk = __builtin_amdgcn_readlane(mytok, i + j);  // SGPR
            v[j] = reinterpret_cast<const float4*>(emb + (size_t)tk * EMB)[lane];
        }
        #pragma unroll
        for (int j = 0; j < 8; ++j) {
            acc.x += v[j].x; acc.y += v[j].y; acc.z += v[j].z; acc.w += v[j].w;
        }
    }
    const float s = 1.0f / NL;
    float4 r; r.x = acc.x * s; r.y = acc.y * s; r.z = acc.z * s; r.w = acc.w * s;
    reinterpret_cast<float4*>(sents + (size_t)sid * EMB)[lane] = r;
}

__device__ __forceinline__ float dot4(float4 a, float4 b) {
    return a.x * b.x + a.y * b.y + a.z * b.z + a.w * b.w;
}

// ---------------------------------------------------------------------------
// Kernel 2 v3: logits[b,c] = sum_s softmax_s(ce[c].s_bs) * (mw[c].s_bs) + b[c]
// Grid (NB, 5): block = (b, 20 classes), 256 threads = 4 waves.
// Wave cg owns classes cbase..cbase+4; lane owns sentences {lane, lane+64}.
// Sents staged in LDS per 32-float e-chunk (read ONCE per block). Weights
// read with wave-uniform addresses (scalar path — off the LDS pipe), each
// float4 amortized over 2 sentences x running dual accumulation. Softmax is
// a pure wave-local shfl reduction (wave holds all 128 sentences).
// ---------------------------------------------------------------------------
#define CB    20
#define TC    5
#define EC    32           // e-chunk floats
#define SROW  36           // LDS row stride (pad 32->36; 144B keeps 16B align)

__global__ __launch_bounds__(256) void k_attn_logits3(
    const float* __restrict__ sents, const float* __restrict__ ce,
    const float* __restrict__ mw,    const float* __restrict__ bias,
    float* __restrict__ out)
{
    const int b  = blockIdx.x;
    const int c0 = blockIdx.y * CB;
    const int t  = threadIdx.x;
    const int cg = __builtin_amdgcn_readfirstlane(t >> 6);  // wave id, uniform
    const int lane = t & 63;

    __shared__ float stile[NS][SROW];            // 18432 B

    float sc[TC][2], tv[TC][2];
    #pragma unroll
    for (int i = 0; i < TC; ++i) { sc[i][0] = sc[i][1] = tv[i][0] = tv[i][1] = 0.f; }

    const int cbase = c0 + cg * TC;
    const float* sbase = sents + (size_t)b * NS * EMB;

    for (int ec = 0; ec < EMB / EC; ++ec) {
        __syncthreads();                         // protect previous chunk reads
        // stage 128 x 32 floats: 1024 float4 over 256 threads
        {
            int i = t;
            #pragma unroll
            for (int r = 0; r < 4; ++r, i += 256) {
                const int s = i >> 3, e4 = i & 7;
                const float4 v = reinterpret_cast<const float4*>(
                    sbase + (size_t)s * EMB + ec * EC)[e4];
                *reinterpret_cast<float4*>(&stile[s][e4 * 4]) = v;
            }
        }
        __syncthreads();

        #pragma unroll
        for (int k4 = 0; k4 < EC / 4; ++k4) {
            const float4 s0 = *reinterpret_cast<const float4*>(&stile[lane][k4 * 4]);
            const float4 s1 = *reinterpret_cast<const float4*>(&stile[lane + 64][k4 * 4]);
            #pragma unroll
            for (int i = 0; i < TC; ++i) {
                const size_t wo = (size_t)(cbase + i) * EMB + ec * EC + k4 * 4;
                const float4 w  = *reinterpret_cast<const float4*>(ce + wo);
                const float4 m4 = *reinterpret_cast<const float4*>(mw + wo);
                sc[i][0] += dot4(s0, w);  sc[i][1] += dot4(s1, w);
                tv[i][0] += dot4(s0, m4); tv[i][1] += dot4(s1, m4);
            }
        }
    }

    // Wave-local softmax-weighted sum per class (lane covers s, s+64).
    #pragma unroll
    for (int i = 0; i < TC; ++i) {
        float m = fmaxf(sc[i][0], sc[i][1]);
        #pragma unroll
        for (int d = 1; d < 64; d <<= 1) m = fmaxf(m, __shfl_xor(m, d));
        const float p0 = __expf(sc[i][0] - m), p1 = __expf(sc[i][1] - m);
        float sp = p0 + p1;
        float st = p0 * tv[i][0] + p1 * tv[i][1];
        #pragma unroll
        for (int d = 1; d < 64; d <<= 1) {
            sp += __shfl_xor(sp, d);
            st += __shfl_xor(st, d);
        }
        if (lane == 0)
            out[(size_t)b * NCLS + cbase + i] = st / sp + bias[cbase + i];
    }
}

extern "C" void kernel_launch(void* const* d_in, const int* in_sizes, int n_in,
                              void* d_out, int out_size, void* d_ws, size_t ws_size,
                              hipStream_t stream)
{
    const int*   tok  = (const int*)  d_in[0];   // (B,S,L) int32
    const float* emb  = (const float*)d_in[1];   // (VOCAB, EMB)
    const float* ce   = (const float*)d_in[2];   // (NCLS, EMB)
    const float* mw   = (const float*)d_in[3];   // (NCLS, EMB)
    const float* bias = (const float*)d_in[4];   // (NCLS, 1)
    float* out   = (float*)d_out;                // (B, NCLS)
    float* sents = (float*)d_ws;                 // NB*NS*EMB floats = 8 MB

    k_gather_mean<<<NB * NS / 4, 256, 0, stream>>>(tok, emb, sents);
    k_attn_logits3<<<dim3(NB, NCLS / CB), 256, 0, stream>>>(sents, ce, mw, bias, out);
}

// Round 6
// 226.548 us; speedup vs baseline: 1.2902x; 1.2902x over previous
//
#include <hip/hip_runtime.h>

#define EMB   256
#define NCLS  100
#define NB    64
#define NS    128
#define NL    64

// ---------------------------------------------------------------------------
// Kernel 1: sents[sid][e] = (1/NL) * sum_l emb[tok[sid,l]][e]
// One WAVE per sentence. Lane covers the 256-float row as float4 (64 lanes x
// 16B = 1KB coalesced per row). Tokens broadcast via v_readlane; loads
// batched 8-deep for MLP. AT THE ~6 TB/s L2-MISS/FABRIC WALL (88 us floor:
// 536 MB demand / 88 us = 6.1 TB/s; duration identical whether served from
// HBM (FETCH=253MB) or L3 (FETCH=8MB) — do not touch).
// ---------------------------------------------------------------------------
__global__ __launch_bounds__(256) void k_gather_mean(
    const int* __restrict__ tok, const float* __restrict__ emb,
    float* __restrict__ sents)
{
    const int w    = threadIdx.x >> 6;
    const int lane = threadIdx.x & 63;
    const int sid  = blockIdx.x * 4 + w;          // grid.x = NB*NS/4 = 2048

    const int mytok = tok[(size_t)sid * NL + lane];   // lane l holds token l

    float4 acc = make_float4(0.f, 0.f, 0.f, 0.f);
    for (int i = 0; i < NL; i += 8) {
        float4 v[8];
        #pragma unroll
        for (int j = 0; j < 8; ++j) {
            const int tk = __builtin_amdgcn_readlane(mytok, i + j);  // SGPR
            v[j] = reinterpret_cast<const float4*>(emb + (size_t)tk * EMB)[lane];
        }
        #pragma unroll
        for (int j = 0; j < 8; ++j) {
            acc.x += v[j].x; acc.y += v[j].y; acc.z += v[j].z; acc.w += v[j].w;
        }
    }
    const float s = 1.0f / NL;
    float4 r; r.x = acc.x * s; r.y = acc.y * s; r.z = acc.z * s; r.w = acc.w * s;
    reinterpret_cast<float4*>(sents + (size_t)sid * EMB)[lane] = r;
}

__device__ __forceinline__ float dot4(float4 a, float4 b) {
    return a.x * b.x + a.y * b.y + a.z * b.z + a.w * b.w;
}

// ---------------------------------------------------------------------------
// Kernel 2 v4: logits[b,c] = sum_s softmax_s(ce[c].s_bs) * (mw[c].s_bs) + b[c]
// v3 was LAUNCH-WIDTH-BOUND: 320 blocks -> 15.6% occupancy cap, 93 us.
// v4: grid (NB, 25), CB=4 classes/block, 256 thr = 4 waves -> 1600 blocks,
// 6400 waves = 78% cap. Wave = one class (weights via wave-uniform scalar
// loads); lane = sentence pair {lane, lane+64}. Sents staged in LDS per
// 32-float e-chunk (coalesced, read once per block; same-b blocks land on
// the same XCD since 64 % 8 == 0 -> L2-resident re-reads). Softmax is one
// wave-local shfl reduction per class.
// ---------------------------------------------------------------------------
#define CB    4
#define EC    32           // e-chunk floats
#define SROW  36           // LDS row stride (pad 32->36; 144B keeps 16B align)

__global__ __launch_bounds__(256) void k_attn_logits4(
    const float* __restrict__ sents, const float* __restrict__ ce,
    const float* __restrict__ mw,    const float* __restrict__ bias,
    float* __restrict__ out)
{
    const int b    = blockIdx.x;
    const int t    = threadIdx.x;
    const int lane = t & 63;
    const int c    = __builtin_amdgcn_readfirstlane(blockIdx.y * CB + (t >> 6));

    __shared__ float stile[NS][SROW];            // 18432 B

    float sc0 = 0.f, sc1 = 0.f, tv0 = 0.f, tv1 = 0.f;

    const float* sbase = sents + (size_t)b * NS * EMB;
    const float* wrow  = ce + (size_t)c * EMB;   // wave-uniform rows
    const float* mrow  = mw + (size_t)c * EMB;

    for (int ec = 0; ec < EMB / EC; ++ec) {
        __syncthreads();                         // protect previous chunk reads
        // stage 128 x 32 floats: 1024 float4 over 256 threads, coalesced
        {
            int i = t;
            #pragma unroll
            for (int r = 0; r < 4; ++r, i += 256) {
                const int s = i >> 3, e4 = i & 7;
                *reinterpret_cast<float4*>(&stile[s][e4 * 4]) =
                    reinterpret_cast<const float4*>(
                        sbase + (size_t)s * EMB + ec * EC)[e4];
            }
        }
        __syncthreads();

        #pragma unroll
        for (int k4 = 0; k4 < EC / 4; ++k4) {
            const float4 s0 = *reinterpret_cast<const float4*>(&stile[lane][k4 * 4]);
            const float4 s1 = *reinterpret_cast<const float4*>(&stile[lane + 64][k4 * 4]);
            const float4 w  = *reinterpret_cast<const float4*>(wrow + ec * EC + k4 * 4);
            const float4 m4 = *reinterpret_cast<const float4*>(mrow + ec * EC + k4 * 4);
            sc0 += dot4(s0, w);  sc1 += dot4(s1, w);
            tv0 += dot4(s0, m4); tv1 += dot4(s1, m4);
        }
    }

    // Wave-local softmax-weighted sum (lane covers sentences lane, lane+64).
    float m = fmaxf(sc0, sc1);
    #pragma unroll
    for (int d = 1; d < 64; d <<= 1) m = fmaxf(m, __shfl_xor(m, d));
    const float p0 = __expf(sc0 - m), p1 = __expf(sc1 - m);
    float sp = p0 + p1;
    float st = p0 * tv0 + p1 * tv1;
    #pragma unroll
    for (int d = 1; d < 64; d <<= 1) {
        sp += __shfl_xor(sp, d);
        st += __shfl_xor(st, d);
    }
    if (lane == 0)
        out[(size_t)b * NCLS + c] = st / sp + bias[c];
}

extern "C" void kernel_launch(void* const* d_in, const int* in_sizes, int n_in,
                              void* d_out, int out_size, void* d_ws, size_t ws_size,
                              hipStream_t stream)
{
    const int*   tok  = (const int*)  d_in[0];   // (B,S,L) int32
    const float* emb  = (const float*)d_in[1];   // (VOCAB, EMB)
    const float* ce   = (const float*)d_in[2];   // (NCLS, EMB)
    const float* mw   = (const float*)d_in[3];   // (NCLS, EMB)
    const float* bias = (const float*)d_in[4];   // (NCLS, 1)
    float* out   = (float*)d_out;                // (B, NCLS)
    float* sents = (float*)d_ws;                 // NB*NS*EMB floats = 8 MB

    k_gather_mean<<<NB * NS / 4, 256, 0, stream>>>(tok, emb, sents);
    k_attn_logits4<<<dim3(NB, NCLS / CB), 256, 0, stream>>>(sents, ce, mw, bias, out);
}